// Round 9
// baseline (60.841 us; speedup 1.0000x reference)
//
#include <hip/hip_runtime.h>
#include <math.h>

#define CLS_NUM 1000
#define FEAT 512
#define N1_BLOCKS 512
#define N1_THREADS 512            // 8 waves/block, 2 blocks/CU -> 16 waves/CU
#define N2_BLOCKS 16
#define N2_THREADS 64

// ---------- helpers ----------

__device__ __forceinline__ bool detect_is64(const void* ys_raw) {
    // int64 (LE): high word of each element is 0, low word < 1000.
    // int32: odd words are random labels; all-zero across 16 slots ~ 1e-48.
    const int* y32 = (const int*)ys_raw;
    bool is64 = true;
#pragma unroll
    for (int k = 0; k < 16; ++k) {
        int lo = y32[2 * k], hi = y32[2 * k + 1];
        if (hi != 0 || (unsigned)lo >= (unsigned)CLS_NUM) is64 = false;
    }
    return is64;
}

__device__ __forceinline__ int load_label(const void* ys_raw, bool is64, int i) {
    return is64 ? (int)((const long long*)ys_raw)[i] : ((const int*)ys_raw)[i];
}

// ---------- node 1: streaming dist pass -> per-block LDS bins -> stored partials ----------
// One wave per sample (512 floats = 64 lanes x 2 float4, fully coalesced).
// All class accumulation stays in per-block LDS (zeroed in-kernel: no global
// memset node, no global atomics). Partials are fully STORED each call.

__global__ __launch_bounds__(N1_THREADS) void dist_bins(
    const float* __restrict__ xs,
    const void* __restrict__ ys_raw,
    const float* __restrict__ center,
    float* __restrict__ distP,       // [N1_BLOCKS][CLS_NUM]
    unsigned* __restrict__ cntP,     // [N1_BLOCKS][CLS_NUM]
    float* __restrict__ out,
    int n)
{
    __shared__ float    dbin[CLS_NUM];
    __shared__ unsigned cbin[CLS_NUM];
    const int t = (int)threadIdx.x;

    for (int c = t; c < CLS_NUM; c += N1_THREADS) { dbin[c] = 0.f; cbin[c] = 0u; }
    __syncthreads();

    const bool is64 = detect_is64(ys_raw);
    const int lane  = t & 63;
    const int wave  = (int)(blockIdx.x * (N1_THREADS / 64) + (t >> 6));
    const int nwave = (int)(gridDim.x * (N1_THREADS / 64));

    for (int i = wave; i < n; i += nwave) {
        const int y = load_label(ys_raw, is64, i);
        const float4* xp = (const float4*)(xs + (size_t)i * FEAT);
        const float4* cp = (const float4*)(center + (size_t)y * FEAT);
        float4 x0 = xp[lane];
        float4 x1 = xp[lane + 64];
        float4 c0 = cp[lane];
        float4 c1 = cp[lane + 64];
        float d, s = 0.f;
        d = x0.x - c0.x; s += d * d;
        d = x0.y - c0.y; s += d * d;
        d = x0.z - c0.z; s += d * d;
        d = x0.w - c0.w; s += d * d;
        d = x1.x - c1.x; s += d * d;
        d = x1.y - c1.y; s += d * d;
        d = x1.z - c1.z; s += d * d;
        d = x1.w - c1.w; s += d * d;
#pragma unroll
        for (int off = 32; off; off >>= 1)
            s += __shfl_xor(s, off, 64);

        if (lane == 0) {
            atomicAdd(&dbin[y], sqrtf(s));   // LDS atomics, ~16/wave total
            atomicAdd(&cbin[y], 1u);
        }
    }
    __syncthreads();

    float*    dp = distP + (size_t)blockIdx.x * CLS_NUM;
    unsigned* cp2 = cntP + (size_t)blockIdx.x * CLS_NUM;
    for (int c = t; c < CLS_NUM; c += N1_THREADS) { dp[c] = dbin[c]; cp2[c] = cbin[c]; }

    if (blockIdx.x == 0 && t == 0) out[0] = 0.f;  // consumed only by node 2
}

// ---------- node 2: column-reduce partials, divide, sum into out ----------
// thread = class (consecutive threads -> consecutive classes -> coalesced
// 256 B per row per block); 512 rows each; 16 global atomics total.

__global__ __launch_bounds__(N2_THREADS) void reduce_bins(
    const float* __restrict__ distP,
    const unsigned* __restrict__ cntP,
    float* __restrict__ out)
{
    const int c = (int)(blockIdx.x * N2_THREADS + threadIdx.x);
    float v = 0.f;
    if (c < CLS_NUM) {
        float ds = 0.f;
        unsigned cnt = 0u;
        for (int r = 0; r < N1_BLOCKS; ++r) {
            ds  += distP[(size_t)r * CLS_NUM + c];
            cnt += cntP[(size_t)r * CLS_NUM + c];
        }
        if (cnt) v = ds / (float)cnt;
    }
#pragma unroll
    for (int off = 32; off; off >>= 1)
        v += __shfl_xor(v, off, 64);
    if (threadIdx.x == 0)
        atomicAdd(out, v);
}

extern "C" void kernel_launch(void* const* d_in, const int* in_sizes, int n_in,
                              void* d_out, int out_size, void* d_ws, size_t ws_size,
                              hipStream_t stream)
{
    const float* xs     = (const float*)d_in[0];
    const void*  ys     = d_in[1];
    const float* center = (const float*)d_in[2];
    float* out = (float*)d_out;

    // ws layout: distP [512][1000] f32 (2.048 MB) ; cntP [512][1000] u32
    float*    distP = (float*)d_ws;
    unsigned* cntP  = (unsigned*)((char*)d_ws + (size_t)N1_BLOCKS * CLS_NUM * 4);

    const int n = in_sizes[1];  // number of samples (ys element count)

    dist_bins<<<N1_BLOCKS, N1_THREADS, 0, stream>>>(xs, ys, center, distP, cntP, out, n);
    reduce_bins<<<N2_BLOCKS, N2_THREADS, 0, stream>>>(distP, cntP, out);
}

// Round 10
// 46.779 us; speedup vs baseline: 1.3006x; 1.3006x over previous
//
#include <hip/hip_runtime.h>
#include <math.h>

#define CLS_NUM 1000
#define FEAT 512

// R2 kernel, resubmitted VERBATIM as an A/B against the 2-node variants
// (R6-R9 all 57-61us; R2 measured 47.3us on the previous container).
// One wave (64 lanes) per sample: 512 floats = 64 lanes x 2 float4.
// Fused pass: per-class dist-sum + per-class count via global atomics
// (1000 bins, ~65 adds/bin, fire-and-forget -> hidden under HBM stream).
__global__ __launch_bounds__(256) void center_loss_dist(
    const float* __restrict__ xs,
    const void* __restrict__ ys_raw,
    const float* __restrict__ center,
    float* __restrict__ distsum,
    unsigned int* __restrict__ count,
    int n)
{
    // Detect int64 vs int32 labels: for int64 (little-endian) the high
    // 32-bit word of each element is 0 and low word < 1000. For int32,
    // odd words are random labels; all-zero across 16 slots ~ 1e-48.
    const int* y32 = (const int*)ys_raw;
    bool is64 = true;
    #pragma unroll
    for (int k = 0; k < 16; ++k) {
        int lo = y32[2 * k], hi = y32[2 * k + 1];
        if (hi != 0 || (unsigned)lo >= (unsigned)CLS_NUM) is64 = false;
    }
    const long long* y64 = (const long long*)ys_raw;

    const int lane  = threadIdx.x & 63;
    const int wave  = (int)((blockIdx.x * blockDim.x + threadIdx.x) >> 6);
    const int nwave = (int)((gridDim.x * blockDim.x) >> 6);

    for (int i = wave; i < n; i += nwave) {
        const int y = is64 ? (int)y64[i] : y32[i];
        const float4* xp = (const float4*)(xs + (size_t)i * FEAT);
        const float4* cp = (const float4*)(center + (size_t)y * FEAT);
        // Fully coalesced: lane l reads float4 #l and #(l+64) of the row.
        float4 x0 = xp[lane];
        float4 x1 = xp[lane + 64];
        float4 c0 = cp[lane];
        float4 c1 = cp[lane + 64];
        float d, s = 0.f;
        d = x0.x - c0.x; s += d * d;
        d = x0.y - c0.y; s += d * d;
        d = x0.z - c0.z; s += d * d;
        d = x0.w - c0.w; s += d * d;
        d = x1.x - c1.x; s += d * d;
        d = x1.y - c1.y; s += d * d;
        d = x1.z - c1.z; s += d * d;
        d = x1.w - c1.w; s += d * d;
        #pragma unroll
        for (int off = 32; off; off >>= 1)
            s += __shfl_xor(s, off, 64);
        if (lane == 0) {
            atomicAdd(&distsum[y], sqrtf(s));
            atomicAdd(&count[y], 1u);
        }
    }
}

// out = sum_c distsum[c] / count[c]   (count>0 guard; absent classes add 0)
__global__ __launch_bounds__(256) void center_loss_final(
    const float* __restrict__ distsum,
    const unsigned int* __restrict__ count,
    float* __restrict__ out)
{
    float s = 0.f;
    for (int c = threadIdx.x; c < CLS_NUM; c += 256) {
        unsigned n = count[c];
        if (n) s += distsum[c] / (float)n;
    }
    #pragma unroll
    for (int off = 32; off; off >>= 1)
        s += __shfl_xor(s, off, 64);
    __shared__ float wsum[4];
    if ((threadIdx.x & 63) == 0) wsum[threadIdx.x >> 6] = s;
    __syncthreads();
    if (threadIdx.x == 0)
        out[0] = wsum[0] + wsum[1] + wsum[2] + wsum[3];
}

extern "C" void kernel_launch(void* const* d_in, const int* in_sizes, int n_in,
                              void* d_out, int out_size, void* d_ws, size_t ws_size,
                              hipStream_t stream)
{
    const float* xs     = (const float*)d_in[0];
    const void*  ys     = d_in[1];
    const float* center = (const float*)d_in[2];
    float* out = (float*)d_out;

    // ws layout: [0,4000) distsum floats ; [4096, 8096) counts
    float* distsum       = (float*)d_ws;
    unsigned int* count  = (unsigned int*)((char*)d_ws + 4096);
    hipMemsetAsync(d_ws, 0, 8192, stream);

    const int n = in_sizes[1];  // number of samples (ys element count)

    center_loss_dist<<<2048, 256, 0, stream>>>(xs, ys, center, distsum, count, n);
    center_loss_final<<<1, 256, 0, stream>>>(distsum, count, out);
}